// Round 12
// baseline (138.844 us; speedup 1.0000x reference)
//
#include <hip/hip_runtime.h>
#include <hip/hip_fp16.h>
#include <math.h>

typedef __attribute__((ext_vector_type(8))) _Float16 half8;
typedef __attribute__((ext_vector_type(4))) _Float16 half4;
typedef __attribute__((ext_vector_type(4))) float f32x4;
typedef __attribute__((ext_vector_type(16))) float f32x16;
typedef __attribute__((ext_vector_type(4))) unsigned uint4v;

#define HQ 16
#define HK 4
#define DH 64
#define NB 2
#define SEQ 2048
#define EDIM 1024
#define KD 1024

// direct global->LDS 16B async copy; LDS dest = wave-uniform base + lane*16
__device__ __forceinline__ void gload16(const void* g, void* l) {
  __builtin_amdgcn_global_load_lds(
      (const __attribute__((address_space(1))) void*)g,
      (__attribute__((address_space(3))) void*)l, 16, 0, 0);
}

__device__ __forceinline__ float vmax16(f32x16 v) {
  float a = fmaxf(fmaxf(v[0], v[1]), v[2]);
  a = fmaxf(fmaxf(a, v[3]), v[4]);
  a = fmaxf(fmaxf(a, v[5]), v[6]);
  a = fmaxf(fmaxf(a, v[7]), v[8]);
  a = fmaxf(fmaxf(a, v[9]), v[10]);
  a = fmaxf(fmaxf(a, v[11]), v[12]);
  a = fmaxf(fmaxf(a, v[13]), v[14]);
  return fmaxf(a, v[15]);
}

// ---------------- prep: convert x to f16 + RoPE table (fused) ----------------
__global__ __launch_bounds__(256) void prep_cvt_rope(
    const float* __restrict__ x, _Float16* __restrict__ xh,
    const int* __restrict__ qpos, float2* __restrict__ tab) {
  int bx = blockIdx.x;
  int tid = threadIdx.x;
  if (bx < 4096) {
    int i = bx * 256 + tid;
    float4 v = ((const float4*)x)[i];
    half4 h;
    h[0] = (_Float16)v.x; h[1] = (_Float16)v.y; h[2] = (_Float16)v.z; h[3] = (_Float16)v.w;
    *(half4*)(xh + (size_t)i * 4) = h;
  } else {
    int i = (bx - 4096) * 256 + tid;     // 0 .. 4096*32-1
    int row = i >> 5, d = i & 31;
    float ang = (float)qpos[row] * expf((float)d * -0.2878231366242558f); // -ln(1e4)/32
    float sn, cs;
    sincosf(ang, &sn, &cs);
    tab[i] = make_float2(sn, cs);
  }
}

// ---------------- prep: all four W [K][N] f32 -> [N][K] f16 (fused) ----------------
__global__ __launch_bounds__(256) void transpose_w4(
    const float* __restrict__ Wq, const float* __restrict__ Wk,
    const float* __restrict__ Wv, const float* __restrict__ Wo,
    _Float16* __restrict__ WT, _Float16* __restrict__ WoT) {
  int z = blockIdx.z;
  const float* W;
  _Float16* dst;
  int N, roff;
  if (z == 0)      { W = Wq; N = 1024; roff = 0;    dst = WT; }
  else if (z == 1) { W = Wk; N = 256;  roff = 1024; dst = WT;  if (blockIdx.x >= 4) return; }
  else if (z == 2) { W = Wv; N = 256;  roff = 1280; dst = WT;  if (blockIdx.x >= 4) return; }
  else             { W = Wo; N = 1024; roff = 0;    dst = WoT; }

  __shared__ float t[64][65];
  int n0 = blockIdx.x * 64, k0 = blockIdx.y * 64;
  int tid = threadIdx.x;
#pragma unroll
  for (int p = 0; p < 4; ++p) {
    int idx = tid + p * 256;
    int r = idx >> 4;      // k row 0..63
    int c4 = idx & 15;     // float4 col
    float4 v = *(const float4*)(W + (size_t)(k0 + r) * N + n0 + c4 * 4);
    t[r][c4 * 4 + 0] = v.x; t[r][c4 * 4 + 1] = v.y;
    t[r][c4 * 4 + 2] = v.z; t[r][c4 * 4 + 3] = v.w;
  }
  __syncthreads();
#pragma unroll
  for (int p = 0; p < 4; ++p) {
    int idx = tid + p * 256;
    int n = idx >> 4;
    int k4 = idx & 15;
    half4 h;
    h[0] = (_Float16)t[k4 * 4 + 0][n]; h[1] = (_Float16)t[k4 * 4 + 1][n];
    h[2] = (_Float16)t[k4 * 4 + 2][n]; h[3] = (_Float16)t[k4 * 4 + 3][n];
    *(half4*)(dst + (size_t)(roff + n0 + n) * KD + k0 + k4 * 4) = h;
  }
}

// ---------------- prep: V [bh][s][d] -> V^T [bh][d][s] ----------------
__global__ __launch_bounds__(256) void transpose_v_kernel(const _Float16* __restrict__ vhp,
                                                          _Float16* __restrict__ vtp) {
  __shared__ _Float16 t[64][72];
  int bh = blockIdx.y;           // 0..7  (b*HK+hk)
  int s0 = blockIdx.x * 64;      // 32 tiles over SEQ
  const _Float16* src = vhp + ((size_t)bh * SEQ + s0) * DH;
  _Float16* dst = vtp + (size_t)bh * DH * SEQ + s0;
  int tid = threadIdx.x;
#pragma unroll
  for (int p = 0; p < 2; ++p) {
    int idx = tid + p * 256;     // 512 half8s
    int r = idx >> 3, c8 = idx & 7;
    half8 v = *(const half8*)(src + (size_t)r * DH + c8 * 8);
#pragma unroll
    for (int i = 0; i < 8; ++i) t[r][c8 * 8 + i] = v[i];
  }
  __syncthreads();
#pragma unroll
  for (int p = 0; p < 2; ++p) {
    int idx = tid + p * 256;
    int d = idx >> 3, c8 = idx & 7;
    half8 v;
#pragma unroll
    for (int i = 0; i < 8; ++i) v[i] = t[c8 * 8 + i][d];
    *(half8*)(dst + (size_t)d * SEQ + c8 * 8) = v;
  }
}

// swizzle: XOR bits 4-6 of the byte offset with row&7 (row stride 128B tiles)
#define SWZ(r, kb) ((kb) ^ (((r) & 7) << 4))

// ---------------- K1: fused QKV GEMM + RoPE (table-driven) ----------------
__global__ __launch_bounds__(256) void gemm_qkv_rope(
    const _Float16* __restrict__ xh, const _Float16* __restrict__ WT,
    const float2* __restrict__ rtab,
    _Float16* __restrict__ qh, _Float16* __restrict__ kh, _Float16* __restrict__ vh) {
  __shared__ char As[128 * 64 * 2];
  __shared__ char Bs[128 * 64 * 2];
  int tid = threadIdx.x, lane = tid & 63, wid = tid >> 6;
  int wr = wid >> 1, wc = wid & 1;
  int bm = blockIdx.x, bn = blockIdx.y;

  const char* Ag = (const char*)(xh + (size_t)bm * 128 * KD);
  const char* Bg = (const char*)(WT + (size_t)bn * 128 * KD);

  int colS = 16 * ((lane & 7) ^ (lane >> 3));      // pre-swizzled source col (bytes)
  int rS = (lane >> 3);

  f32x4 acc[4][4] = {};

  for (int kt = 0; kt < KD / 64; ++kt) {
#pragma unroll
    for (int p = 0; p < 4; ++p) {
      int r = (wid * 4 + p) * 8 + rS;
      gload16(Ag + (size_t)r * (KD * 2) + kt * 128 + colS, As + (wid * 4 + p) * 1024);
      gload16(Bg + (size_t)r * (KD * 2) + kt * 128 + colS, Bs + (wid * 4 + p) * 1024);
    }
    __syncthreads();
#pragma unroll
    for (int kk = 0; kk < 2; ++kk) {
      int kb = kk * 64 + (lane >> 4) * 16;
      half8 af[4], bf[4];
#pragma unroll
      for (int mf = 0; mf < 4; ++mf) {
        int r = wr * 64 + mf * 16 + (lane & 15);
        af[mf] = *(const half8*)(As + r * 128 + SWZ(r, kb));
      }
#pragma unroll
      for (int nf = 0; nf < 4; ++nf) {
        int r = wc * 64 + nf * 16 + (lane & 15);
        bf[nf] = *(const half8*)(Bs + r * 128 + SWZ(r, kb));
      }
#pragma unroll
      for (int mf = 0; mf < 4; ++mf)
#pragma unroll
        for (int nf = 0; nf < 4; ++nf)
          acc[mf][nf] = __builtin_amdgcn_mfma_f32_16x16x32_f16(af[mf], bf[nf], acc[mf][nf], 0, 0, 0);
    }
    __syncthreads();
  }

  int col0 = bn * 128 + wc * 64;
  int row_base = bm * 128 + wr * 64;
#pragma unroll
  for (int mf = 0; mf < 4; ++mf) {
#pragma unroll
    for (int j = 0; j < 4; ++j) {
      int row = row_base + mf * 16 + (lane >> 4) * 4 + j;
      int b = row >> 11, s = row & (SEQ - 1);
      if (col0 < 1024) {
        int hq = col0 >> 6;
        size_t base = (((size_t)b * HQ + hq) * SEQ + s) * DH;
#pragma unroll
        for (int nf = 0; nf < 2; ++nf) {
          int d = nf * 16 + (lane & 15);  // 0..31
          float2 scv = rtab[row * 32 + d];
          float x1 = acc[mf][nf][j], x2 = acc[mf][nf + 2][j];
          qh[base + d]      = (_Float16)(x1 * scv.y - x2 * scv.x);
          qh[base + d + 32] = (_Float16)(x2 * scv.y + x1 * scv.x);
        }
      } else if (col0 < 1280) {
        int hk = (col0 - 1024) >> 6;
        size_t base = (((size_t)b * HK + hk) * SEQ + s) * DH;
#pragma unroll
        for (int nf = 0; nf < 2; ++nf) {
          int d = nf * 16 + (lane & 15);
          float2 scv = rtab[row * 32 + d];
          float x1 = acc[mf][nf][j], x2 = acc[mf][nf + 2][j];
          kh[base + d]      = (_Float16)(x1 * scv.y - x2 * scv.x);
          kh[base + d + 32] = (_Float16)(x2 * scv.y + x1 * scv.x);
        }
      } else {
        int hk = (col0 - 1280) >> 6;
        size_t base = (((size_t)b * HK + hk) * SEQ + s) * DH;
#pragma unroll
        for (int nf = 0; nf < 4; ++nf) {
          int d = nf * 16 + (lane & 15);
          vh[base + d] = (_Float16)acc[mf][nf][j];
        }
      }
    }
  }
}

// ---------------- K2: flash attention, per-b4 online softmax, KV-split ----------------
// grid: (qt=16, bh=32, sp=2). block 256 = 4 waves x 32 q-rows. KV tile = 128.
// Single live sacc (16 regs) instead of sacc[4] (64) -> lower reg footprint ->
// 3 waves/SIMD target. Defer-max THR=8 (log2 domain). unroll 1 stops rehoisting.
__global__ __launch_bounds__(256) void attn_kernel(
    const _Float16* __restrict__ qh, const _Float16* __restrict__ kh,
    const _Float16* __restrict__ vt, _Float16* __restrict__ o0,
    _Float16* __restrict__ o1, float2* __restrict__ ml) {
  __shared__ char Ks[128 * 64 * 2];      // 16KB [kv][d] swz, row 128B
  __shared__ char Vs[64 * 128 * 2];      // 16KB [d][kv] swz, row 256B

  int tid = threadIdx.x, lane = tid & 63, wid = tid >> 6;
  int half = lane >> 5, l31 = lane & 31;
  bool lopart = (half == 0);
  int qt = blockIdx.x, bh = blockIdx.y, sp = blockIdx.z;
  int b = bh >> 4, hq = bh & 15, hk = hq >> 2;
  int kv0 = sp * (SEQ / 2);

  const _Float16* Qg = qh + (((size_t)b * HQ + hq) * SEQ + qt * 128 + wid * 32 + l31) * DH;
  const char* Kg = (const char*)(kh + (((size_t)b * HK + hk) * SEQ) * DH);
  const char* Vtg = (const char*)(vt + (size_t)(b * HK + hk) * DH * SEQ);

  // Q as B-fragments: lane holds Q[q=l31][d = ks*16 + half*8 + i], pre-scaled
  const _Float16 l2e = (_Float16)1.44269504f;
  half8 qf[4];
#pragma unroll
  for (int ks = 0; ks < 4; ++ks) {
    half8 q0 = *(const half8*)(Qg + ks * 16 + half * 8);
#pragma unroll
    for (int i = 0; i < 8; ++i) q0[i] = q0[i] * l2e;
    qf[ks] = q0;
  }

  // staging addressing (pre-swizzled source so linear LDS dest = swz layout)
  int colK = 16 * ((lane & 7) ^ (lane >> 3));
  int rKl = lane >> 3;

  f32x16 oacc[2] = {};   // O^T: lane q=l31, d=dblk*32+(r&3)+8*(r>>2)+4*half
  float m = -3e38f, l = 0.f;

  for (int kt = 0; kt < SEQ / 2 / 128; ++kt) {
    // stage K [128 kv][64 d] and V^T [64 d][128 kv]: 8 gload16 per thread
#pragma unroll
    for (int p = 0; p < 4; ++p) {
      int sb = wid * 4 + p;                 // 0..15
      int r = sb * 8 + rKl;
      gload16(Kg + (size_t)(kv0 + kt * 128 + r) * 128 + colK, Ks + sb * 1024);
      int d = sb * 4 + (lane >> 4);
      int colV = ((lane & 15) * 16) ^ ((d & 7) << 4);
      gload16(Vtg + (size_t)d * (SEQ * 2) + (kv0 + kt * 128) * 2 + colV, Vs + sb * 1024);
    }
    asm volatile("s_waitcnt vmcnt(0)" ::: "memory");
    __builtin_amdgcn_s_barrier();

    // per 32-kv block: QK -> online max -> exp/pack -> PV (single sacc live)
#pragma unroll 1
    for (int b4 = 0; b4 < 4; ++b4) {
      f32x16 sacc = {};
      int r = b4 * 32 + l31;
      __builtin_amdgcn_s_setprio(1);
#pragma unroll
      for (int ks = 0; ks < 4; ++ks) {
        half8 kf = *(const half8*)(Ks + r * 128 + SWZ(r, ks * 32 + half * 16));
        sacc = __builtin_amdgcn_mfma_f32_32x32x16_f16(kf, qf[ks], sacc, 0, 0, 0);
      }
      __builtin_amdgcn_s_setprio(0);

      float pm = vmax16(sacc);
      pm = fmaxf(pm, __shfl_xor(pm, 32, 64));
      if (__any(pm > m + 8.f)) {          // defer-max: P bounded by 2^8
        float mnew = fmaxf(m, pm);
        float alpha = __builtin_amdgcn_exp2f(m - mnew);
        m = mnew;
        l *= alpha;
        oacc[0] *= alpha;
        oacc[1] *= alpha;
      }

      float e[16];
      float ps = 0.f;
#pragma unroll
      for (int rr = 0; rr < 16; ++rr) {
        e[rr] = __builtin_amdgcn_exp2f(sacc[rr] - m);
        ps += e[rr];
      }
      unsigned W0[4], W1[4];
#pragma unroll
      for (int qd = 0; qd < 4; ++qd) {
        W0[qd] = __builtin_bit_cast(unsigned, __builtin_amdgcn_cvt_pkrtz(e[4 * qd + 0], e[4 * qd + 1]));
        W1[qd] = __builtin_bit_cast(unsigned, __builtin_amdgcn_cvt_pkrtz(e[4 * qd + 2], e[4 * qd + 3]));
      }
      half8 pf[2];
#pragma unroll
      for (int s = 0; s < 2; ++s) {
        unsigned selA = lopart ? W0[2 * s + 1] : W0[2 * s];
        unsigned crA = (unsigned)__shfl_xor((int)selA, 32, 64);
        unsigned selB = lopart ? W1[2 * s + 1] : W1[2 * s];
        unsigned crB = (unsigned)__shfl_xor((int)selB, 32, 64);
        uint4v u;
        u[0] = lopart ? W0[2 * s] : crA;
        u[1] = lopart ? W1[2 * s] : crB;
        u[2] = lopart ? crA : W0[2 * s + 1];
        u[3] = lopart ? crB : W1[2 * s + 1];
        pf[s] = __builtin_bit_cast(half8, u);
      }
      __builtin_amdgcn_s_setprio(1);
#pragma unroll
      for (int s = 0; s < 2; ++s) {
        int kvb = b4 * 64 + s * 32 + half * 16;
#pragma unroll
        for (int dblk = 0; dblk < 2; ++dblk) {
          int d = dblk * 32 + l31;
          half8 vf = *(const half8*)(Vs + d * 256 + SWZ(d, kvb));
          oacc[dblk] = __builtin_amdgcn_mfma_f32_32x32x16_f16(vf, pf[s], oacc[dblk], 0, 0, 0);
        }
      }
      __builtin_amdgcn_s_setprio(0);

      ps += __shfl_xor(ps, 32, 64);
      l += ps;
    }
    __builtin_amdgcn_s_barrier();    // all waves done reading before next stage
  }

  // write normalized partial O + (m,l); lane owns q = l31
  int s = qt * 128 + wid * 32 + l31;
  float invl = 1.f / l;
  _Float16* op = sp ? o1 : o0;
  size_t base = ((size_t)b * SEQ + s) * 1024 + hq * 64;
#pragma unroll
  for (int dblk = 0; dblk < 2; ++dblk) {
#pragma unroll
    for (int qd = 0; qd < 4; ++qd) {
      half4 o;
#pragma unroll
      for (int j = 0; j < 4; ++j) o[j] = (_Float16)(oacc[dblk][qd * 4 + j] * invl);
      *(half4*)(op + base + dblk * 32 + qd * 8 + half * 4) = o;
    }
  }
  if (half == 0)
    ml[((size_t)(sp * NB + b) * HQ + hq) * SEQ + s] = make_float2(m, l);
}

// ---------------- K2b: combine the two KV-split partials ----------------
__global__ __launch_bounds__(256) void combine_kernel(
    const _Float16* __restrict__ o0, const _Float16* __restrict__ o1,
    const float2* __restrict__ ml, _Float16* __restrict__ oh) {
  int idx = blockIdx.x * 256 + threadIdx.x;   // 524288 half8s
  size_t h0 = (size_t)idx * 8;
  int row = (int)(h0 >> 6);        // (b*SEQ+s)*16 + hq
  int hq = row & 15;
  int bs = row >> 4;
  int b = bs >> 11, s = bs & (SEQ - 1);
  float2 ml0 = ml[((size_t)(0 * NB + b) * HQ + hq) * SEQ + s];
  float2 ml1 = ml[((size_t)(1 * NB + b) * HQ + hq) * SEQ + s];
  float mm = fmaxf(ml0.x, ml1.x);
  float w0 = __builtin_amdgcn_exp2f(ml0.x - mm) * ml0.y;
  float w1 = __builtin_amdgcn_exp2f(ml1.x - mm) * ml1.y;
  float inv = 1.f / (w0 + w1);
  float s0 = w0 * inv, s1 = w1 * inv;
  half8 v0 = *(const half8*)(o0 + h0);
  half8 v1 = *(const half8*)(o1 + h0);
  half8 o;
#pragma unroll
  for (int i = 0; i < 8; ++i)
    o[i] = (_Float16)((float)v0[i] * s0 + (float)v1[i] * s1);
  *(half8*)(oh + h0) = o;
}

// ---------------- K3: output projection, fp32 out ----------------
__global__ __launch_bounds__(256) void gemm_out(
    const _Float16* __restrict__ ah, const _Float16* __restrict__ WoT,
    float* __restrict__ out) {
  __shared__ char As[128 * 64 * 2];
  __shared__ char Bs[128 * 64 * 2];
  int tid = threadIdx.x, lane = tid & 63, wid = tid >> 6;
  int wr = wid >> 1, wc = wid & 1;
  int bm = blockIdx.x, bn = blockIdx.y;
  const char* Ag = (const char*)(ah + (size_t)bm * 128 * KD);
  const char* Bg = (const char*)(WoT + (size_t)bn * 128 * KD);
  int colS = 16 * ((lane & 7) ^ (lane >> 3));
  int rS = (lane >> 3);
  f32x4 acc[4][4] = {};

  for (int kt = 0; kt < KD / 64; ++kt) {
#pragma unroll
    for (int p = 0; p < 4; ++p) {
      int r = (wid * 4 + p) * 8 + rS;
      gload16(Ag + (size_t)r * (KD * 2) + kt * 128 + colS, As + (wid * 4 + p) * 1024);
      gload16(Bg + (size_t)r * (KD * 2) + kt * 128 + colS, Bs + (wid * 4 + p) * 1024);
    }
    __syncthreads();
#pragma unroll
    for (int kk = 0; kk < 2; ++kk) {
      int kb = kk * 64 + (lane >> 4) * 16;
      half8 af[4], bf[4];
#pragma unroll
      for (int mf = 0; mf < 4; ++mf) {
        int r = wr * 64 + mf * 16 + (lane & 15);
        af[mf] = *(const half8*)(As + r * 128 + SWZ(r, kb));
      }
#pragma unroll
      for (int nf = 0; nf < 4; ++nf) {
        int r = wc * 64 + nf * 16 + (lane & 15);
        bf[nf] = *(const half8*)(Bs + r * 128 + SWZ(r, kb));
      }
#pragma unroll
      for (int mf = 0; mf < 4; ++mf)
#pragma unroll
        for (int nf = 0; nf < 4; ++nf)
          acc[mf][nf] = __builtin_amdgcn_mfma_f32_16x16x32_f16(af[mf], bf[nf], acc[mf][nf], 0, 0, 0);
    }
    __syncthreads();
  }

  int row0 = bm * 128 + wr * 64, col0 = bn * 128 + wc * 64;
#pragma unroll
  for (int mf = 0; mf < 4; ++mf)
#pragma unroll
    for (int j = 0; j < 4; ++j) {
      int row = row0 + mf * 16 + (lane >> 4) * 4 + j;
#pragma unroll
      for (int nf = 0; nf < 4; ++nf)
        out[(size_t)row * 1024 + col0 + nf * 16 + (lane & 15)] = acc[mf][nf][j];
    }
}

// ---------------- launch ----------------
extern "C" void kernel_launch(void* const* d_in, const int* in_sizes, int n_in,
                              void* d_out, int out_size, void* d_ws, size_t ws_size,
                              hipStream_t stream) {
  const float* x  = (const float*)d_in[0];
  const int* qpos = (const int*)d_in[1];
  const float* Wq = (const float*)d_in[2];
  const float* Wk = (const float*)d_in[3];
  const float* Wv = (const float*)d_in[4];
  const float* Wo = (const float*)d_in[5];
  float* out = (float*)d_out;

  char* ws = (char*)d_ws;
  _Float16* xh  = (_Float16*)(ws);                 // 8 MB  [4096][1024] (dead after gemm_qkv)
  _Float16* WT  = (_Float16*)(ws + 8388608);       // 3 MB  (dead after gemm_qkv)
  _Float16* WoT = (_Float16*)(ws + 11534336);      // 2 MB  [1024][1024]
  _Float16* qhp = (_Float16*)(ws + 13631488);      // 8 MB  [B][HQ][S][D]
  _Float16* khp = (_Float16*)(ws + 22020096);      // 2 MB  [B][HK][S][D]
  _Float16* vhp = (_Float16*)(ws + 24117248);      // 2 MB  [B][HK][S][D]
  _Float16* ohp = (_Float16*)(ws + 26214400);      // 8 MB  [4096][1024] (= split-0 partial)
  float2*   rtab = (float2*)(ws + 34603008);       // 1 MB  [4096][32]
  _Float16* vtp = (_Float16*)(ws + 35651584);      // 2 MB  [B][HK][D][S]
  _Float16* op1 = (_Float16*)(ws);                 // 8 MB  split-1 partial (reuses xh)
  float2*   mlb = (float2*)(ws + 8388608);         // 1 MB  (m,l) per split (reuses WT)

  prep_cvt_rope<<<4608, 256, 0, stream>>>(x, xh, qpos, rtab);
  transpose_w4<<<dim3(16, 16, 4), 256, 0, stream>>>(Wq, Wk, Wv, Wo, WT, WoT);
  gemm_qkv_rope<<<dim3(32, 12), 256, 0, stream>>>(xh, WT, rtab, qhp, khp, vhp);
  transpose_v_kernel<<<dim3(32, 8), 256, 0, stream>>>(vhp, vtp);
  attn_kernel<<<dim3(16, 32, 2), 256, 0, stream>>>(qhp, khp, vtp, ohp, op1, mlb);
  combine_kernel<<<2048, 256, 0, stream>>>(ohp, op1, mlb, ohp);
  gemm_out<<<dim3(32, 8), 256, 0, stream>>>(ohp, WoT, out);
}

// Round 13
// 109.246 us; speedup vs baseline: 1.2709x; 1.2709x over previous
//
#include <hip/hip_runtime.h>
#include <hip/hip_fp16.h>
#include <math.h>

typedef __attribute__((ext_vector_type(8))) _Float16 half8;
typedef __attribute__((ext_vector_type(4))) _Float16 half4;
typedef __attribute__((ext_vector_type(4))) float f32x4;
typedef __attribute__((ext_vector_type(16))) float f32x16;
typedef __attribute__((ext_vector_type(4))) unsigned uint4v;

#define HQ 16
#define HK 4
#define DH 64
#define NB 2
#define SEQ 2048
#define EDIM 1024
#define KD 1024

// direct global->LDS 16B async copy; LDS dest = wave-uniform base + lane*16
__device__ __forceinline__ void gload16(const void* g, void* l) {
  __builtin_amdgcn_global_load_lds(
      (const __attribute__((address_space(1))) void*)g,
      (__attribute__((address_space(3))) void*)l, 16, 0, 0);
}

// ---------------- prep: convert x to f16 + RoPE table (fused) ----------------
__global__ __launch_bounds__(256) void prep_cvt_rope(
    const float* __restrict__ x, _Float16* __restrict__ xh,
    const int* __restrict__ qpos, float2* __restrict__ tab) {
  int bx = blockIdx.x;
  int tid = threadIdx.x;
  if (bx < 4096) {
    int i = bx * 256 + tid;
    float4 v = ((const float4*)x)[i];
    half4 h;
    h[0] = (_Float16)v.x; h[1] = (_Float16)v.y; h[2] = (_Float16)v.z; h[3] = (_Float16)v.w;
    *(half4*)(xh + (size_t)i * 4) = h;
  } else {
    int i = (bx - 4096) * 256 + tid;     // 0 .. 4096*32-1
    int row = i >> 5, d = i & 31;
    float ang = (float)qpos[row] * expf((float)d * -0.2878231366242558f); // -ln(1e4)/32
    float sn, cs;
    sincosf(ang, &sn, &cs);
    tab[i] = make_float2(sn, cs);
  }
}

// ---------------- prep: all four W [K][N] f32 -> [N][K] f16 (fused) ----------------
__global__ __launch_bounds__(256) void transpose_w4(
    const float* __restrict__ Wq, const float* __restrict__ Wk,
    const float* __restrict__ Wv, const float* __restrict__ Wo,
    _Float16* __restrict__ WT, _Float16* __restrict__ WoT) {
  int z = blockIdx.z;
  const float* W;
  _Float16* dst;
  int N, roff;
  if (z == 0)      { W = Wq; N = 1024; roff = 0;    dst = WT; }
  else if (z == 1) { W = Wk; N = 256;  roff = 1024; dst = WT;  if (blockIdx.x >= 4) return; }
  else if (z == 2) { W = Wv; N = 256;  roff = 1280; dst = WT;  if (blockIdx.x >= 4) return; }
  else             { W = Wo; N = 1024; roff = 0;    dst = WoT; }

  __shared__ float t[64][65];
  int n0 = blockIdx.x * 64, k0 = blockIdx.y * 64;
  int tid = threadIdx.x;
#pragma unroll
  for (int p = 0; p < 4; ++p) {
    int idx = tid + p * 256;
    int r = idx >> 4;      // k row 0..63
    int c4 = idx & 15;     // float4 col
    float4 v = *(const float4*)(W + (size_t)(k0 + r) * N + n0 + c4 * 4);
    t[r][c4 * 4 + 0] = v.x; t[r][c4 * 4 + 1] = v.y;
    t[r][c4 * 4 + 2] = v.z; t[r][c4 * 4 + 3] = v.w;
  }
  __syncthreads();
#pragma unroll
  for (int p = 0; p < 4; ++p) {
    int idx = tid + p * 256;
    int n = idx >> 4;
    int k4 = idx & 15;
    half4 h;
    h[0] = (_Float16)t[k4 * 4 + 0][n]; h[1] = (_Float16)t[k4 * 4 + 1][n];
    h[2] = (_Float16)t[k4 * 4 + 2][n]; h[3] = (_Float16)t[k4 * 4 + 3][n];
    *(half4*)(dst + (size_t)(roff + n0 + n) * KD + k0 + k4 * 4) = h;
  }
}

// ---------------- prep: V [bh][s][d] -> V^T [bh][d][s] ----------------
__global__ __launch_bounds__(256) void transpose_v_kernel(const _Float16* __restrict__ vhp,
                                                          _Float16* __restrict__ vtp) {
  __shared__ _Float16 t[64][72];
  int bh = blockIdx.y;           // 0..7  (b*HK+hk)
  int s0 = blockIdx.x * 64;      // 32 tiles over SEQ
  const _Float16* src = vhp + ((size_t)bh * SEQ + s0) * DH;
  _Float16* dst = vtp + (size_t)bh * DH * SEQ + s0;
  int tid = threadIdx.x;
#pragma unroll
  for (int p = 0; p < 2; ++p) {
    int idx = tid + p * 256;     // 512 half8s
    int r = idx >> 3, c8 = idx & 7;
    half8 v = *(const half8*)(src + (size_t)r * DH + c8 * 8);
#pragma unroll
    for (int i = 0; i < 8; ++i) t[r][c8 * 8 + i] = v[i];
  }
  __syncthreads();
#pragma unroll
  for (int p = 0; p < 2; ++p) {
    int idx = tid + p * 256;
    int d = idx >> 3, c8 = idx & 7;
    half8 v;
#pragma unroll
    for (int i = 0; i < 8; ++i) v[i] = t[c8 * 8 + i][d];
    *(half8*)(dst + (size_t)d * SEQ + c8 * 8) = v;
  }
}

// swizzle: XOR bits 4-6 of the byte offset with row&7 (row stride 128B tiles)
#define SWZ(r, kb) ((kb) ^ (((r) & 7) << 4))

// ---------------- K1: fused QKV GEMM + RoPE, BM=64 x BN=128 ----------------
// grid (64,12) = 768 blocks -> ~3 blocks/CU (was 1.5). LDS 24KB.
// 4 waves in 2x2; wave-tile 32x64 = acc[2][4].
__global__ __launch_bounds__(256) void gemm_qkv_rope(
    const _Float16* __restrict__ xh, const _Float16* __restrict__ WT,
    const float2* __restrict__ rtab,
    _Float16* __restrict__ qh, _Float16* __restrict__ kh, _Float16* __restrict__ vh) {
  __shared__ char As[64 * 64 * 2];     // 8KB  [m][k] swz, row 128B
  __shared__ char Bs[128 * 64 * 2];    // 16KB [n][k] swz, row 128B
  int tid = threadIdx.x, lane = tid & 63, wid = tid >> 6;
  int wr = wid >> 1, wc = wid & 1;
  int bm = blockIdx.x, bn = blockIdx.y;

  const char* Ag = (const char*)(xh + (size_t)bm * 64 * KD);
  const char* Bg = (const char*)(WT + (size_t)bn * 128 * KD);

  int colS = 16 * ((lane & 7) ^ (lane >> 3));      // pre-swizzled source col (bytes)
  int rS = (lane >> 3);

  f32x4 acc[2][4] = {};

  for (int kt = 0; kt < KD / 64; ++kt) {
#pragma unroll
    for (int p = 0; p < 2; ++p) {                  // A: 8 slots over 4 waves
      int sb = wid * 2 + p;
      int r = sb * 8 + rS;
      gload16(Ag + (size_t)r * (KD * 2) + kt * 128 + colS, As + sb * 1024);
    }
#pragma unroll
    for (int p = 0; p < 4; ++p) {                  // B: 16 slots over 4 waves
      int sb = wid * 4 + p;
      int r = sb * 8 + rS;
      gload16(Bg + (size_t)r * (KD * 2) + kt * 128 + colS, Bs + sb * 1024);
    }
    __syncthreads();
#pragma unroll
    for (int kk = 0; kk < 2; ++kk) {
      int kb = kk * 64 + (lane >> 4) * 16;
      half8 af[2], bf[4];
#pragma unroll
      for (int mf = 0; mf < 2; ++mf) {
        int r = wr * 32 + mf * 16 + (lane & 15);
        af[mf] = *(const half8*)(As + r * 128 + SWZ(r, kb));
      }
#pragma unroll
      for (int nf = 0; nf < 4; ++nf) {
        int r = wc * 64 + nf * 16 + (lane & 15);
        bf[nf] = *(const half8*)(Bs + r * 128 + SWZ(r, kb));
      }
#pragma unroll
      for (int mf = 0; mf < 2; ++mf)
#pragma unroll
        for (int nf = 0; nf < 4; ++nf)
          acc[mf][nf] = __builtin_amdgcn_mfma_f32_16x16x32_f16(af[mf], bf[nf], acc[mf][nf], 0, 0, 0);
    }
    __syncthreads();
  }

  // epilogue: wave covers 64 contiguous cols = exactly one head
  int col0 = bn * 128 + wc * 64;
  int row_base = bm * 64 + wr * 32;
#pragma unroll
  for (int mf = 0; mf < 2; ++mf) {
#pragma unroll
    for (int j = 0; j < 4; ++j) {
      int row = row_base + mf * 16 + (lane >> 4) * 4 + j;
      int b = row >> 11, s = row & (SEQ - 1);
      if (col0 < 1024) {
        int hq = col0 >> 6;
        size_t base = (((size_t)b * HQ + hq) * SEQ + s) * DH;
#pragma unroll
        for (int nf = 0; nf < 2; ++nf) {
          int d = nf * 16 + (lane & 15);  // 0..31
          float2 scv = rtab[row * 32 + d];
          float x1 = acc[mf][nf][j], x2 = acc[mf][nf + 2][j];
          qh[base + d]      = (_Float16)(x1 * scv.y - x2 * scv.x);
          qh[base + d + 32] = (_Float16)(x2 * scv.y + x1 * scv.x);
        }
      } else if (col0 < 1280) {
        int hk = (col0 - 1024) >> 6;
        size_t base = (((size_t)b * HK + hk) * SEQ + s) * DH;
#pragma unroll
        for (int nf = 0; nf < 2; ++nf) {
          int d = nf * 16 + (lane & 15);
          float2 scv = rtab[row * 32 + d];
          float x1 = acc[mf][nf][j], x2 = acc[mf][nf + 2][j];
          kh[base + d]      = (_Float16)(x1 * scv.y - x2 * scv.x);
          kh[base + d + 32] = (_Float16)(x2 * scv.y + x1 * scv.x);
        }
      } else {
        int hk = (col0 - 1280) >> 6;
        size_t base = (((size_t)b * HK + hk) * SEQ + s) * DH;
#pragma unroll
        for (int nf = 0; nf < 4; ++nf) {
          int d = nf * 16 + (lane & 15);
          vh[base + d] = (_Float16)acc[mf][nf][j];
        }
      }
    }
  }
}

// ---------------- K2: flash attention (R8 body: 32x32 MFMA, in-reg P, dbuf) ----------------
// grid: (qt=16, bh=32). block 256 = 4 waves x 32 q-rows. KV tile = 128.
// Double-buffered LDS, global_load_lds with pre-swizzled source, counted vmcnt(8).
__global__ __launch_bounds__(256) void attn_kernel(
    const _Float16* __restrict__ qh, const _Float16* __restrict__ kh,
    const _Float16* __restrict__ vt, _Float16* __restrict__ oh) {
  __shared__ char Ks[2][128 * 64 * 2];   // 2x16KB [kv][d] swz, row 128B
  __shared__ char Vs[2][64 * 128 * 2];   // 2x16KB [d][kv] swz, row 256B

  int tid = threadIdx.x, lane = tid & 63, wid = tid >> 6;
  int half = lane >> 5, l31 = lane & 31;
  bool lopart = (half == 0);
  int qt = blockIdx.x, bh = blockIdx.y;
  int b = bh >> 4, hq = bh & 15, hk = hq >> 2;

  const _Float16* Qg = qh + (((size_t)b * HQ + hq) * SEQ + qt * 128 + wid * 32 + l31) * DH;
  const char* Kg = (const char*)(kh + (((size_t)b * HK + hk) * SEQ) * DH);
  const char* Vtg = (const char*)(vt + (size_t)(b * HK + hk) * DH * SEQ);

  // Q as B-fragments: lane holds Q[q=l31][d = ks*16 + half*8 + i], pre-scaled
  const _Float16 l2e = (_Float16)1.44269504f;
  half8 qf[4];
#pragma unroll
  for (int ks = 0; ks < 4; ++ks) {
    half8 q0 = *(const half8*)(Qg + ks * 16 + half * 8);
#pragma unroll
    for (int i = 0; i < 8; ++i) q0[i] = q0[i] * l2e;
    qf[ks] = q0;
  }

  // staging source addressing (pre-swizzled so linear LDS dest = swizzled layout)
  int colK = 16 * ((lane & 7) ^ (lane >> 3));      // K: fixed per lane
  int rK = lane >> 3;

  f32x16 oacc[2] = {};   // O^T: lane q=l31, d=dblk*32+(r&3)+8*(r>>2)+4*half
  float m = -3e38f, l = 0.f;

  // prologue: stage tile 0 into buf 0
#pragma unroll
  for (int p = 0; p < 4; ++p) {
    int r = (wid * 4 + p) * 8 + rK;
    gload16(Kg + (size_t)r * 128 + colK, Ks[0] + (wid * 4 + p) * 1024);
    int d = (wid * 4 + p) * 4 + (lane >> 4);
    int colV = ((lane & 15) * 16) ^ ((d & 7) << 4);
    gload16(Vtg + (size_t)d * (SEQ * 2) + colV, Vs[0] + (wid * 4 + p) * 1024);
  }

  int cur = 0;
  for (int kt = 0; kt < SEQ / 128; ++kt) {
    if (kt + 1 < SEQ / 128) {
      // issue next tile into the other buffer; stays in flight across compute
#pragma unroll
      for (int p = 0; p < 4; ++p) {
        int r = (wid * 4 + p) * 8 + rK;
        gload16(Kg + (size_t)((kt + 1) * 128 + r) * 128 + colK,
                Ks[cur ^ 1] + (wid * 4 + p) * 1024);
        int d = (wid * 4 + p) * 4 + (lane >> 4);
        int colV = ((lane & 15) * 16) ^ ((d & 7) << 4);
        gload16(Vtg + (size_t)d * (SEQ * 2) + (kt + 1) * 256 + colV,
                Vs[cur ^ 1] + (wid * 4 + p) * 1024);
      }
      asm volatile("s_waitcnt vmcnt(8)" ::: "memory");   // current tile's 8 done
    } else {
      asm volatile("s_waitcnt vmcnt(0)" ::: "memory");
    }
    __builtin_amdgcn_s_barrier();                        // all waves' cur loads done
    const char* KsB = Ks[cur];
    const char* VsB = Vs[cur];

    // S^T = K Q^T : 4 kv-blocks of 32, K-dim d=64 in 4 slices of 16
    f32x16 sacc[4] = {};
    __builtin_amdgcn_s_setprio(1);
#pragma unroll
    for (int b4 = 0; b4 < 4; ++b4) {
      int r = b4 * 32 + l31;
#pragma unroll
      for (int ks = 0; ks < 4; ++ks) {
        half8 kf = *(const half8*)(KsB + r * 128 + SWZ(r, ks * 32 + half * 16));
        sacc[b4] = __builtin_amdgcn_mfma_f32_32x32x16_f16(kf, qf[ks], sacc[b4], 0, 0, 0);
      }
    }
    __builtin_amdgcn_s_setprio(0);

    // row max: lane's 64 values + partner (lane^32)
    float pm = sacc[0][0];
#pragma unroll
    for (int b4 = 0; b4 < 4; ++b4)
#pragma unroll
      for (int r = 0; r < 16; ++r)
        if (b4 || r) pm = fmaxf(pm, sacc[b4][r]);
    pm = fmaxf(pm, __shfl_xor(pm, 32, 64));
    float mnew = fmaxf(m, pm);
    float alpha = __builtin_amdgcn_exp2f(m - mnew);
    m = mnew;
    oacc[0] *= alpha;
    oacc[1] *= alpha;
    l *= alpha;
    float ps = 0.f;

    // per kv-block: exp, pack, build PV B-frags in-register, PV MFMA
#pragma unroll
    for (int b4 = 0; b4 < 4; ++b4) {
      float e[16];
#pragma unroll
      for (int r = 0; r < 16; ++r) {
        e[r] = __builtin_amdgcn_exp2f(sacc[b4][r] - m);
        ps += e[r];
      }
      unsigned W0[4], W1[4];
#pragma unroll
      for (int qd = 0; qd < 4; ++qd) {
        W0[qd] = __builtin_bit_cast(unsigned, __builtin_amdgcn_cvt_pkrtz(e[4 * qd + 0], e[4 * qd + 1]));
        W1[qd] = __builtin_bit_cast(unsigned, __builtin_amdgcn_cvt_pkrtz(e[4 * qd + 2], e[4 * qd + 3]));
      }
      half8 pf[2];
#pragma unroll
      for (int s = 0; s < 2; ++s) {
        unsigned selA = lopart ? W0[2 * s + 1] : W0[2 * s];
        unsigned crA = (unsigned)__shfl_xor((int)selA, 32, 64);
        unsigned selB = lopart ? W1[2 * s + 1] : W1[2 * s];
        unsigned crB = (unsigned)__shfl_xor((int)selB, 32, 64);
        uint4v u;
        u[0] = lopart ? W0[2 * s] : crA;
        u[1] = lopart ? W1[2 * s] : crB;
        u[2] = lopart ? crA : W0[2 * s + 1];
        u[3] = lopart ? crB : W1[2 * s + 1];
        pf[s] = __builtin_bit_cast(half8, u);
      }
      __builtin_amdgcn_s_setprio(1);
#pragma unroll
      for (int s = 0; s < 2; ++s) {
        int kvb = b4 * 64 + s * 32 + half * 16;
#pragma unroll
        for (int dblk = 0; dblk < 2; ++dblk) {
          int d = dblk * 32 + l31;
          half8 vf = *(const half8*)(VsB + d * 256 + SWZ(d, kvb));
          oacc[dblk] = __builtin_amdgcn_mfma_f32_32x32x16_f16(vf, pf[s], oacc[dblk], 0, 0, 0);
        }
      }
      __builtin_amdgcn_s_setprio(0);
    }
    ps += __shfl_xor(ps, 32, 64);
    l += ps;
    __builtin_amdgcn_s_barrier();    // all waves done reading cur before overwrite
    cur ^= 1;
  }

  // normalize + write [B][S][HQ*DH]; lane owns q = l31, 32 d-values per dblk
  int s = qt * 128 + wid * 32 + l31;
  float invl = 1.f / l;
  size_t base = ((size_t)b * SEQ + s) * 1024 + hq * 64;
#pragma unroll
  for (int dblk = 0; dblk < 2; ++dblk) {
#pragma unroll
    for (int qd = 0; qd < 4; ++qd) {
      half4 o;
#pragma unroll
      for (int j = 0; j < 4; ++j) o[j] = (_Float16)(oacc[dblk][qd * 4 + j] * invl);
      *(half4*)(oh + base + dblk * 32 + qd * 8 + half * 4) = o;
    }
  }
}

// ---------------- K3: output projection, BM=64 x BN=128, fp32 out ----------------
// grid (64,8) = 512 blocks -> 2 blocks/CU (was 1.0).
__global__ __launch_bounds__(256) void gemm_out(
    const _Float16* __restrict__ ah, const _Float16* __restrict__ WoT,
    float* __restrict__ out) {
  __shared__ char As[64 * 64 * 2];     // 8KB
  __shared__ char Bs[128 * 64 * 2];    // 16KB
  int tid = threadIdx.x, lane = tid & 63, wid = tid >> 6;
  int wr = wid >> 1, wc = wid & 1;
  int bm = blockIdx.x, bn = blockIdx.y;
  const char* Ag = (const char*)(ah + (size_t)bm * 64 * KD);
  const char* Bg = (const char*)(WoT + (size_t)bn * 128 * KD);
  int colS = 16 * ((lane & 7) ^ (lane >> 3));
  int rS = (lane >> 3);
  f32x4 acc[2][4] = {};

  for (int kt = 0; kt < KD / 64; ++kt) {
#pragma unroll
    for (int p = 0; p < 2; ++p) {
      int sb = wid * 2 + p;
      int r = sb * 8 + rS;
      gload16(Ag + (size_t)r * (KD * 2) + kt * 128 + colS, As + sb * 1024);
    }
#pragma unroll
    for (int p = 0; p < 4; ++p) {
      int sb = wid * 4 + p;
      int r = sb * 8 + rS;
      gload16(Bg + (size_t)r * (KD * 2) + kt * 128 + colS, Bs + sb * 1024);
    }
    __syncthreads();
#pragma unroll
    for (int kk = 0; kk < 2; ++kk) {
      int kb = kk * 64 + (lane >> 4) * 16;
      half8 af[2], bf[4];
#pragma unroll
      for (int mf = 0; mf < 2; ++mf) {
        int r = wr * 32 + mf * 16 + (lane & 15);
        af[mf] = *(const half8*)(As + r * 128 + SWZ(r, kb));
      }
#pragma unroll
      for (int nf = 0; nf < 4; ++nf) {
        int r = wc * 64 + nf * 16 + (lane & 15);
        bf[nf] = *(const half8*)(Bs + r * 128 + SWZ(r, kb));
      }
#pragma unroll
      for (int mf = 0; mf < 2; ++mf)
#pragma unroll
        for (int nf = 0; nf < 4; ++nf)
          acc[mf][nf] = __builtin_amdgcn_mfma_f32_16x16x32_f16(af[mf], bf[nf], acc[mf][nf], 0, 0, 0);
    }
    __syncthreads();
  }

  int row0 = bm * 64 + wr * 32, col0 = bn * 128 + wc * 64;
#pragma unroll
  for (int mf = 0; mf < 2; ++mf)
#pragma unroll
    for (int j = 0; j < 4; ++j) {
      int row = row0 + mf * 16 + (lane >> 4) * 4 + j;
#pragma unroll
      for (int nf = 0; nf < 4; ++nf)
        out[(size_t)row * 1024 + col0 + nf * 16 + (lane & 15)] = acc[mf][nf][j];
    }
}

// ---------------- launch ----------------
extern "C" void kernel_launch(void* const* d_in, const int* in_sizes, int n_in,
                              void* d_out, int out_size, void* d_ws, size_t ws_size,
                              hipStream_t stream) {
  const float* x  = (const float*)d_in[0];
  const int* qpos = (const int*)d_in[1];
  const float* Wq = (const float*)d_in[2];
  const float* Wk = (const float*)d_in[3];
  const float* Wv = (const float*)d_in[4];
  const float* Wo = (const float*)d_in[5];
  float* out = (float*)d_out;

  char* ws = (char*)d_ws;
  _Float16* xh  = (_Float16*)(ws);                 // 8 MB  [4096][1024]
  _Float16* WT  = (_Float16*)(ws + 8388608);       // 3 MB  [1536][1024] (q,k,v stacked)
  _Float16* WoT = (_Float16*)(ws + 11534336);      // 2 MB  [1024][1024]
  _Float16* qhp = (_Float16*)(ws + 13631488);      // 8 MB  [B][HQ][S][D]
  _Float16* khp = (_Float16*)(ws + 22020096);      // 2 MB  [B][HK][S][D]
  _Float16* vhp = (_Float16*)(ws + 24117248);      // 2 MB  [B][HK][S][D]
  _Float16* ohp = (_Float16*)(ws + 26214400);      // 8 MB  [4096][1024]
  float2*   rtab = (float2*)(ws + 34603008);       // 1 MB  [4096][32]
  _Float16* vtp = (_Float16*)(ws + 35651584);      // 2 MB  [B][HK][D][S]

  prep_cvt_rope<<<4608, 256, 0, stream>>>(x, xh, qpos, rtab);
  transpose_w4<<<dim3(16, 16, 4), 256, 0, stream>>>(Wq, Wk, Wv, Wo, WT, WoT);
  gemm_qkv_rope<<<dim3(64, 12), 256, 0, stream>>>(xh, WT, rtab, qhp, khp, vhp);
  transpose_v_kernel<<<dim3(32, 8), 256, 0, stream>>>(vhp, vtp);
  attn_kernel<<<dim3(16, 32), 256, 0, stream>>>(qhp, khp, vtp, ohp);
  gemm_out<<<dim3(64, 8), 256, 0, stream>>>(ohp, WoT, out);
}